// Round 5
// baseline (168.891 us; speedup 1.0000x reference)
//
#include <hip/hip_runtime.h>

#define H 4096
#define W 4096
#define TH 16          // rows per edge block
#define BX 256         // threads per block
#define GX 4           // 4096 cols / (256 thr * 4 cols)
#define GY (H / TH)    // 256
#define NEDGE (GX * GY)   // 1024 edge blocks
#define NKPB 16           // keypoint blocks (64 kp each, 1024 total)

#define MASK_W 1.0f
#define KPT_W 0.5f

struct RowData { float v0, v1, v2, v3, lf, rf; };
struct Prep { float dx0, dx1, dx2, dx3, s0, s1, s2, s3; };

__device__ __forceinline__ float fast_sqrt(float x) {
    return __builtin_amdgcn_sqrtf(x);   // raw v_sqrt_f32 (~1 ulp)
}

// Load 4 contiguous pixels + left/right halo. Halo comes from neighbor lanes
// via shuffle; only wave-edge lanes (0 and 63) do a tiny predicated load.
__device__ __forceinline__ RowData loadrow_fast(const float* __restrict__ rowptr,
                                                int c, bool rvalid) {
    float4 v;
    if (rvalid) v = *(const float4*)rowptr;
    else        v = make_float4(0.f, 0.f, 0.f, 0.f);
    RowData rd;
    rd.v0 = v.x; rd.v1 = v.y; rd.v2 = v.z; rd.v3 = v.w;
    rd.lf = __shfl_up(v.w, 1);    // lane l  <- lane l-1 .v3  == img[c-1]
    rd.rf = __shfl_down(v.x, 1);  // lane l  <- lane l+1 .v0  == img[c+4]
    int lane = threadIdx.x & 63;
    if (lane == 0 || lane == 63) {
        bool left = (lane == 0);
        bool ok = rvalid && (left ? (c > 0) : (c + 4 < W));
        const float* q = left ? (rowptr - 1) : (rowptr + 4);
        float h = ok ? *q : 0.f;
        if (left) rd.lf = h; else rd.rf = h;
    }
    return rd;
}

__device__ __forceinline__ Prep prep(const RowData& rd) {
    Prep o;
    o.dx0 = rd.v1 - rd.lf;
    o.dx1 = rd.v2 - rd.v0;
    o.dx2 = rd.v3 - rd.v1;
    o.dx3 = rd.rf - rd.v2;
    o.s0 = __fmaf_rn(2.f, rd.v0, rd.lf + rd.v1);
    o.s1 = __fmaf_rn(2.f, rd.v1, rd.v0 + rd.v2);
    o.s2 = __fmaf_rn(2.f, rd.v2, rd.v1 + rd.v3);
    o.s3 = __fmaf_rn(2.f, rd.v3, rd.v2 + rd.rf);
    return o;
}

__device__ __forceinline__ float edge1(float dxA, float dxB, float dxC, float sA, float sC) {
    float ex = dxA + __fmaf_rn(2.f, dxB, dxC);
    float ey = sC - sA;
    return fast_sqrt(__fmaf_rn(ex, ex, ey * ey));
}

__global__ __launch_bounds__(BX) void fused_kernel(const float* __restrict__ pred,
                                                   const float* __restrict__ targ,
                                                   const float* __restrict__ kp,
                                                   float* __restrict__ ws) {
    int bid = blockIdx.x;

    if (bid < NEDGE) {
        // ======================= edge-loss tile =======================
        int gx = bid & (GX - 1);
        int gy = bid >> 2;           // log2(GX)=2
        int c  = gx * (BX * 4) + threadIdx.x * 4;
        int r0 = gy * TH;

        const float* prow = pred + (size_t)r0 * W + c;
        const float* trow = targ + (size_t)r0 * W + c;

        Prep pA = prep(loadrow_fast(prow - W, c, r0 > 0));
        Prep pB = prep(loadrow_fast(prow,     c, true));
        Prep tA = prep(loadrow_fast(trow - W, c, r0 > 0));
        Prep tB = prep(loadrow_fast(trow,     c, true));
        RowData pn = loadrow_fast(prow + W, c, true);   // r0+1 always valid (TH>=2)
        RowData tn = loadrow_fast(trow + W, c, true);
        prow += 2 * (size_t)W;   // points at r0+2 (next prefetch)
        trow += 2 * (size_t)W;

        float acc = 0.f;
        #pragma unroll 4
        for (int i = 0; i < TH; ++i) {
            RowData pc = pn, tc = tn;
            if (i < TH - 1) {                       // prefetch row r0+i+2
                bool nvalid = (r0 + i + 2) < H;     // false only in last block's last prefetch
                pn = loadrow_fast(prow, c, nvalid);
                tn = loadrow_fast(trow, c, nvalid);
                prow += W; trow += W;
            }
            Prep pC = prep(pc);
            Prep tC = prep(tc);

            float pe, te, d;
            pe = edge1(pA.dx0, pB.dx0, pC.dx0, pA.s0, pC.s0);
            te = edge1(tA.dx0, tB.dx0, tC.dx0, tA.s0, tC.s0);
            d = pe - te; acc = __fmaf_rn(d, d, acc);
            pe = edge1(pA.dx1, pB.dx1, pC.dx1, pA.s1, pC.s1);
            te = edge1(tA.dx1, tB.dx1, tC.dx1, tA.s1, tC.s1);
            d = pe - te; acc = __fmaf_rn(d, d, acc);
            pe = edge1(pA.dx2, pB.dx2, pC.dx2, pA.s2, pC.s2);
            te = edge1(tA.dx2, tB.dx2, tC.dx2, tA.s2, tC.s2);
            d = pe - te; acc = __fmaf_rn(d, d, acc);
            pe = edge1(pA.dx3, pB.dx3, pC.dx3, pA.s3, pC.s3);
            te = edge1(tA.dx3, tB.dx3, tC.dx3, tA.s3, tC.s3);
            d = pe - te; acc = __fmaf_rn(d, d, acc);

            pA = pB; pB = pC;
            tA = tB; tB = tC;
        }

        // wave reduce (width 64)
        #pragma unroll
        for (int m = 32; m; m >>= 1) acc += __shfl_xor(acc, m);

        __shared__ float wsum[BX / 64];
        if ((threadIdx.x & 63) == 0) wsum[threadIdx.x >> 6] = acc;
        __syncthreads();
        if (threadIdx.x == 0) {
            float s = 0.f;
            #pragma unroll
            for (int i = 0; i < BX / 64; ++i) s += wsum[i];
            ws[bid] = s;
        }
    } else {
        // ======================= keypoint block =======================
        int t = threadIdx.x;
        if (t >= 64) return;
        int k = (bid - NEDGE) * 64 + t;        // keypoint index 0..1023

        float gx = kp[2 * k];
        float gy = kp[2 * k + 1];
        float x = (gx + 1.f) * (W * 0.5f) - 0.5f;
        float y = (gy + 1.f) * (H * 0.5f) - 0.5f;
        float fx0 = floorf(x), fy0 = floorf(y);
        int x0 = (int)fx0, y0 = (int)fy0;
        int x1 = x0 + 1, y1 = y0 + 1;
        float wx1 = x - fx0, wx0 = 1.f - wx1;
        float wy1 = y - fy0, wy0 = 1.f - wy1;

        // 6x6 pred_seg patch around (y0, x0), zero-padded
        float sg[6][6];
        #pragma unroll
        for (int i = 0; i < 6; ++i) {
            int rr = y0 - 2 + i;
            #pragma unroll
            for (int j = 0; j < 6; ++j) {
                int cc = x0 - 2 + j;
                bool ok = (rr >= 0) & (rr < H) & (cc >= 0) & (cc < W);
                sg[i][j] = ok ? pred[(size_t)rr * W + cc] : 0.f;
            }
        }

        // 4x4 pred_edge for rows y0-1..y0+2, cols x0-1..x0+2 (0 when OOB)
        float e[4][4];
        #pragma unroll
        for (int i = 0; i < 4; ++i) {
            int rr = y0 - 1 + i;
            #pragma unroll
            for (int j = 0; j < 4; ++j) {
                int cc = x0 - 1 + j;
                if (rr < 0 || rr >= H || cc < 0 || cc >= W) { e[i][j] = 0.f; continue; }
                float ex = (sg[i][j + 2] - sg[i][j])
                         + 2.f * (sg[i + 1][j + 2] - sg[i + 1][j])
                         + (sg[i + 2][j + 2] - sg[i + 2][j]);
                float ey = (sg[i + 2][j] + 2.f * sg[i + 2][j + 1] + sg[i + 2][j + 2])
                         - (sg[i][j] + 2.f * sg[i][j + 1] + sg[i][j + 2]);
                e[i][j] = fast_sqrt(__fmaf_rn(ex, ex, ey * ey));
            }
        }

        // 2x2 distance-map values (3x3 box over pred_edge), zero-padded conv
        float dmap[2][2];
        #pragma unroll
        for (int a = 0; a < 2; ++a) {
            #pragma unroll
            for (int b = 0; b < 2; ++b) {
                float s = 0.f;
                #pragma unroll
                for (int i = 0; i < 3; ++i)
                    #pragma unroll
                    for (int j = 0; j < 3; ++j) s += e[a + i][b + j];
                dmap[a][b] = s;
            }
        }

        bool vx0 = (x0 >= 0) & (x0 < W), vx1 = (x1 >= 0) & (x1 < W);
        bool vy0 = (y0 >= 0) & (y0 < H), vy1 = (y1 >= 0) & (y1 < H);
        float v00 = (vx0 & vy0) ? dmap[0][0] : 0.f;
        float v01 = (vx1 & vy0) ? dmap[0][1] : 0.f;
        float v10 = (vx0 & vy1) ? dmap[1][0] : 0.f;
        float v11 = (vx1 & vy1) ? dmap[1][1] : 0.f;
        float kd = wx0 * wy0 * v00 + wx1 * wy0 * v01
                 + wx0 * wy1 * v10 + wx1 * wy1 * v11;

        // wave reduce 64 kd values
        #pragma unroll
        for (int m = 32; m; m >>= 1) kd += __shfl_xor(kd, m);
        if (t == 0) ws[NEDGE + (bid - NEDGE)] = kd;
    }
}

__global__ __launch_bounds__(256) void final_kernel(const float* __restrict__ ws,
                                                    float* __restrict__ out) {
    int t = threadIdx.x;
    float es = 0.f;
    #pragma unroll
    for (int i = 0; i < NEDGE / 256; ++i) es += ws[t + i * 256];
    float ks = (t < NKPB) ? ws[NEDGE + t] : 0.f;

    #pragma unroll
    for (int m = 32; m; m >>= 1) {
        es += __shfl_xor(es, m);
        ks += __shfl_xor(ks, m);
    }
    __shared__ float res[4], rks[4];
    int wid = t >> 6;
    if ((t & 63) == 0) { res[wid] = es; rks[wid] = ks; }
    __syncthreads();
    if (t == 0) {
        float e2 = res[0] + res[1] + res[2] + res[3];
        float k2 = rks[0] + rks[1] + rks[2] + rks[3];
        float edge_loss = e2 * (1.f / ((float)H * (float)W));
        float constraint_loss = k2 * (1.f / 1024.f);
        out[0] = MASK_W * edge_loss + KPT_W * constraint_loss;
    }
}

extern "C" void kernel_launch(void* const* d_in, const int* in_sizes, int n_in,
                              void* d_out, int out_size, void* d_ws, size_t ws_size,
                              hipStream_t stream) {
    const float* kp   = (const float*)d_in[0];
    const float* pred = (const float*)d_in[2];
    const float* targ = (const float*)d_in[3];
    float* out = (float*)d_out;
    float* ws  = (float*)d_ws;

    fused_kernel<<<NEDGE + NKPB, BX, 0, stream>>>(pred, targ, kp, ws);
    final_kernel<<<1, 256, 0, stream>>>(ws, out);
}

// Round 6
// 155.691 us; speedup vs baseline: 1.0848x; 1.0848x over previous
//
#include <hip/hip_runtime.h>

#define H 4096
#define W 4096
#define TH 8           // rows per edge block
#define BX 256         // threads per block
#define GX 4           // 4096 cols / (256 thr * 4 cols)
#define GY (H / TH)    // 512
#define NEDGE (GX * GY)   // 2048 edge blocks
#define NKPB 16           // keypoint blocks (64 kp each, 1024 total)

#define MASK_W 1.0f
#define KPT_W 0.5f

struct Raw { float4 v; float lf, rf; };              // raw row: no cross-lane ops yet
struct RowData { float v0, v1, v2, v3, lf, rf; };
struct Prep { float dx0, dx1, dx2, dx3, s0, s1, s2, s3; };

__device__ __forceinline__ float fast_sqrt(float x) {
    return __builtin_amdgcn_sqrtf(x);   // raw v_sqrt_f32 (~1 ulp)
}

// Issue loads only — NO shuffles here (they would force an immediate vmcnt
// wait on the just-issued load and destroy the software pipeline).
__device__ __forceinline__ Raw loadraw(const float* __restrict__ rowptr,
                                       int c, bool rvalid, int lane) {
    Raw r;
    if (rvalid) r.v = *(const float4*)rowptr;
    else        r.v = make_float4(0.f, 0.f, 0.f, 0.f);
    r.lf = 0.f; r.rf = 0.f;
    if (lane == 0)  { if (rvalid & (c > 0))     r.lf = rowptr[-1]; }
    if (lane == 63) { if (rvalid & (c + 4 < W)) r.rf = rowptr[4];  }
    return r;
}

// Cross-lane halo resolution — called one iteration AFTER the load was issued.
__device__ __forceinline__ RowData finalize(const Raw& r, int lane) {
    RowData rd;
    rd.v0 = r.v.x; rd.v1 = r.v.y; rd.v2 = r.v.z; rd.v3 = r.v.w;
    float lf = __shfl_up(r.v.w, 1);    // lane l <- lane l-1 .w  == img[c-1]
    float rf = __shfl_down(r.v.x, 1);  // lane l <- lane l+1 .x  == img[c+4]
    rd.lf = (lane == 0)  ? r.lf : lf;
    rd.rf = (lane == 63) ? r.rf : rf;
    return rd;
}

__device__ __forceinline__ Prep prep(const RowData& rd) {
    Prep o;
    o.dx0 = rd.v1 - rd.lf;
    o.dx1 = rd.v2 - rd.v0;
    o.dx2 = rd.v3 - rd.v1;
    o.dx3 = rd.rf - rd.v2;
    o.s0 = __fmaf_rn(2.f, rd.v0, rd.lf + rd.v1);
    o.s1 = __fmaf_rn(2.f, rd.v1, rd.v0 + rd.v2);
    o.s2 = __fmaf_rn(2.f, rd.v2, rd.v1 + rd.v3);
    o.s3 = __fmaf_rn(2.f, rd.v3, rd.v2 + rd.rf);
    return o;
}

__device__ __forceinline__ float edge1(float dxA, float dxB, float dxC, float sA, float sC) {
    float ex = dxA + __fmaf_rn(2.f, dxB, dxC);
    float ey = sC - sA;
    return fast_sqrt(__fmaf_rn(ex, ex, ey * ey));
}

__global__ __launch_bounds__(BX) void fused_kernel(const float* __restrict__ pred,
                                                   const float* __restrict__ targ,
                                                   const float* __restrict__ kp,
                                                   float* __restrict__ ws) {
    int bid = blockIdx.x;

    if (bid < NEDGE) {
        // ======================= edge-loss tile =======================
        int gx = bid & (GX - 1);
        int gy = bid >> 2;           // log2(GX)=2
        int c  = gx * (BX * 4) + threadIdx.x * 4;
        int r0 = gy * TH;
        int lane = threadIdx.x & 63;

        const float* prow = pred + (size_t)r0 * W + c;
        const float* trow = targ + (size_t)r0 * W + c;

        // issue all pipeline-fill loads first (4 rows x 2 images in flight)
        Raw rpA = loadraw(prow - W, c, r0 > 0, lane);
        Raw rtA = loadraw(trow - W, c, r0 > 0, lane);
        Raw rpB = loadraw(prow,     c, true,   lane);
        Raw rtB = loadraw(trow,     c, true,   lane);
        Raw rpn = loadraw(prow + W, c, true,   lane);   // row r0+1 (TH>=2)
        Raw rtn = loadraw(trow + W, c, true,   lane);
        prow += 2 * (size_t)W;   // points at r0+2 (next prefetch)
        trow += 2 * (size_t)W;

        Prep pA = prep(finalize(rpA, lane));
        Prep tA = prep(finalize(rtA, lane));
        Prep pB = prep(finalize(rpB, lane));
        Prep tB = prep(finalize(rtB, lane));

        float acc = 0.f;
        #pragma unroll
        for (int i = 0; i < TH; ++i) {
            Raw rpc = rpn, rtc = rtn;           // row i+1 (loaded last iter)
            if (i < TH - 1) {                   // issue loads for row i+2
                bool nv = (r0 + i + 2) < H;
                rpn = loadraw(prow, c, nv, lane);
                rtn = loadraw(trow, c, nv, lane);
                prow += W; trow += W;
            }
            Prep pC = prep(finalize(rpc, lane));
            Prep tC = prep(finalize(rtc, lane));

            float pe, te, d;
            pe = edge1(pA.dx0, pB.dx0, pC.dx0, pA.s0, pC.s0);
            te = edge1(tA.dx0, tB.dx0, tC.dx0, tA.s0, tC.s0);
            d = pe - te; acc = __fmaf_rn(d, d, acc);
            pe = edge1(pA.dx1, pB.dx1, pC.dx1, pA.s1, pC.s1);
            te = edge1(tA.dx1, tB.dx1, tC.dx1, tA.s1, tC.s1);
            d = pe - te; acc = __fmaf_rn(d, d, acc);
            pe = edge1(pA.dx2, pB.dx2, pC.dx2, pA.s2, pC.s2);
            te = edge1(tA.dx2, tB.dx2, tC.dx2, tA.s2, tC.s2);
            d = pe - te; acc = __fmaf_rn(d, d, acc);
            pe = edge1(pA.dx3, pB.dx3, pC.dx3, pA.s3, pC.s3);
            te = edge1(tA.dx3, tB.dx3, tC.dx3, tA.s3, tC.s3);
            d = pe - te; acc = __fmaf_rn(d, d, acc);

            pA = pB; pB = pC;
            tA = tB; tB = tC;
        }

        // wave reduce (width 64)
        #pragma unroll
        for (int m = 32; m; m >>= 1) acc += __shfl_xor(acc, m);

        __shared__ float wsum[BX / 64];
        if ((threadIdx.x & 63) == 0) wsum[threadIdx.x >> 6] = acc;
        __syncthreads();
        if (threadIdx.x == 0) {
            float s = 0.f;
            #pragma unroll
            for (int i = 0; i < BX / 64; ++i) s += wsum[i];
            ws[bid] = s;
        }
    } else {
        // ======================= keypoint block =======================
        int t = threadIdx.x;
        if (t >= 64) return;
        int k = (bid - NEDGE) * 64 + t;        // keypoint index 0..1023

        float gx = kp[2 * k];
        float gy = kp[2 * k + 1];
        float x = (gx + 1.f) * (W * 0.5f) - 0.5f;
        float y = (gy + 1.f) * (H * 0.5f) - 0.5f;
        float fx0 = floorf(x), fy0 = floorf(y);
        int x0 = (int)fx0, y0 = (int)fy0;
        int x1 = x0 + 1, y1 = y0 + 1;
        float wx1 = x - fx0, wx0 = 1.f - wx1;
        float wy1 = y - fy0, wy0 = 1.f - wy1;

        // 6x6 pred_seg patch around (y0, x0), zero-padded
        float sg[6][6];
        #pragma unroll
        for (int i = 0; i < 6; ++i) {
            int rr = y0 - 2 + i;
            #pragma unroll
            for (int j = 0; j < 6; ++j) {
                int cc = x0 - 2 + j;
                bool ok = (rr >= 0) & (rr < H) & (cc >= 0) & (cc < W);
                sg[i][j] = ok ? pred[(size_t)rr * W + cc] : 0.f;
            }
        }

        // 4x4 pred_edge for rows y0-1..y0+2, cols x0-1..x0+2 (0 when OOB)
        float e[4][4];
        #pragma unroll
        for (int i = 0; i < 4; ++i) {
            int rr = y0 - 1 + i;
            #pragma unroll
            for (int j = 0; j < 4; ++j) {
                int cc = x0 - 1 + j;
                if (rr < 0 || rr >= H || cc < 0 || cc >= W) { e[i][j] = 0.f; continue; }
                float ex = (sg[i][j + 2] - sg[i][j])
                         + 2.f * (sg[i + 1][j + 2] - sg[i + 1][j])
                         + (sg[i + 2][j + 2] - sg[i + 2][j]);
                float ey = (sg[i + 2][j] + 2.f * sg[i + 2][j + 1] + sg[i + 2][j + 2])
                         - (sg[i][j] + 2.f * sg[i][j + 1] + sg[i][j + 2]);
                e[i][j] = fast_sqrt(__fmaf_rn(ex, ex, ey * ey));
            }
        }

        // 2x2 distance-map values (3x3 box over pred_edge), zero-padded conv
        float dmap[2][2];
        #pragma unroll
        for (int a = 0; a < 2; ++a) {
            #pragma unroll
            for (int b = 0; b < 2; ++b) {
                float s = 0.f;
                #pragma unroll
                for (int i = 0; i < 3; ++i)
                    #pragma unroll
                    for (int j = 0; j < 3; ++j) s += e[a + i][b + j];
                dmap[a][b] = s;
            }
        }

        bool vx0 = (x0 >= 0) & (x0 < W), vx1 = (x1 >= 0) & (x1 < W);
        bool vy0 = (y0 >= 0) & (y0 < H), vy1 = (y1 >= 0) & (y1 < H);
        float v00 = (vx0 & vy0) ? dmap[0][0] : 0.f;
        float v01 = (vx1 & vy0) ? dmap[0][1] : 0.f;
        float v10 = (vx0 & vy1) ? dmap[1][0] : 0.f;
        float v11 = (vx1 & vy1) ? dmap[1][1] : 0.f;
        float kd = wx0 * wy0 * v00 + wx1 * wy0 * v01
                 + wx0 * wy1 * v10 + wx1 * wy1 * v11;

        // wave reduce 64 kd values
        #pragma unroll
        for (int m = 32; m; m >>= 1) kd += __shfl_xor(kd, m);
        if (t == 0) ws[NEDGE + (bid - NEDGE)] = kd;
    }
}

__global__ __launch_bounds__(256) void final_kernel(const float* __restrict__ ws,
                                                    float* __restrict__ out) {
    int t = threadIdx.x;
    float es = 0.f;
    #pragma unroll
    for (int i = 0; i < NEDGE / 256; ++i) es += ws[t + i * 256];
    float ks = (t < NKPB) ? ws[NEDGE + t] : 0.f;

    #pragma unroll
    for (int m = 32; m; m >>= 1) {
        es += __shfl_xor(es, m);
        ks += __shfl_xor(ks, m);
    }
    __shared__ float res[4], rks[4];
    int wid = t >> 6;
    if ((t & 63) == 0) { res[wid] = es; rks[wid] = ks; }
    __syncthreads();
    if (t == 0) {
        float e2 = res[0] + res[1] + res[2] + res[3];
        float k2 = rks[0] + rks[1] + rks[2] + rks[3];
        float edge_loss = e2 * (1.f / ((float)H * (float)W));
        float constraint_loss = k2 * (1.f / 1024.f);
        out[0] = MASK_W * edge_loss + KPT_W * constraint_loss;
    }
}

extern "C" void kernel_launch(void* const* d_in, const int* in_sizes, int n_in,
                              void* d_out, int out_size, void* d_ws, size_t ws_size,
                              hipStream_t stream) {
    const float* kp   = (const float*)d_in[0];
    const float* pred = (const float*)d_in[2];
    const float* targ = (const float*)d_in[3];
    float* out = (float*)d_out;
    float* ws  = (float*)d_ws;

    fused_kernel<<<NEDGE + NKPB, BX, 0, stream>>>(pred, targ, kp, ws);
    final_kernel<<<1, 256, 0, stream>>>(ws, out);
}

// Round 7
// 154.626 us; speedup vs baseline: 1.0923x; 1.0069x over previous
//
#include <hip/hip_runtime.h>

#define H 4096
#define W 4096
#define TH 4           // output rows per edge block
#define NR (TH + 2)    // staged rows (with vertical halo)
#define BX 256         // threads per block
#define GX 4           // 4096 cols / (256 thr * 4 cols)
#define GY (H / TH)    // 1024
#define NEDGE (GX * GY)   // 4096 edge blocks
#define NKPB 16           // keypoint blocks (64 kp each, 1024 total)

#define MASK_W 1.0f
#define KPT_W 0.5f

struct Prep { float dx0, dx1, dx2, dx3, s0, s1, s2, s3; };

__device__ __forceinline__ float fast_sqrt(float x) {
    return __builtin_amdgcn_sqrtf(x);   // raw v_sqrt_f32 (~1 ulp)
}

// Cross-lane halo resolution + horizontal Sobel prep. Called at CONSUME time,
// long after the loads were issued (shuffles force a wait on the row's load).
__device__ __forceinline__ Prep fin(float4 v, float h, bool isL, bool isR) {
    float lf = __shfl_up(v.w, 1);    // lane l <- lane l-1 .w  == img[c-1]
    float rf = __shfl_down(v.x, 1);  // lane l <- lane l+1 .x  == img[c+4]
    lf = isL ? h : lf;               // wave-edge lanes use their scalar halo load
    rf = isR ? h : rf;
    Prep o;
    o.dx0 = v.y - lf;
    o.dx1 = v.z - v.x;
    o.dx2 = v.w - v.y;
    o.dx3 = rf  - v.z;
    o.s0 = __fmaf_rn(2.f, v.x, lf  + v.y);
    o.s1 = __fmaf_rn(2.f, v.y, v.x + v.z);
    o.s2 = __fmaf_rn(2.f, v.z, v.y + v.w);
    o.s3 = __fmaf_rn(2.f, v.w, v.z + rf);
    return o;
}

__device__ __forceinline__ float edge1(float dxA, float dxB, float dxC, float sA, float sC) {
    float ex = dxA + __fmaf_rn(2.f, dxB, dxC);
    float ey = sC - sA;
    return fast_sqrt(__fmaf_rn(ex, ex, ey * ey));
}

__global__ __launch_bounds__(BX) void fused_kernel(const float* __restrict__ pred,
                                                   const float* __restrict__ targ,
                                                   const float* __restrict__ kp,
                                                   float* __restrict__ ws) {
    int bid = blockIdx.x;

    if (bid < NEDGE) {
        // ======================= edge-loss tile =======================
        int gx = bid & (GX - 1);
        int gy = bid >> 2;           // log2(GX)=2
        int c  = gx * (BX * 4) + threadIdx.x * 4;
        int r0 = gy * TH;
        int lane = threadIdx.x & 63;
        bool isL = (lane == 0), isR = (lane == 63);
        bool haloCol = (isL & (c > 0)) | (isR & (c + 4 < W));

        const float* bp = pred + (size_t)r0 * W + c;   // row r0
        const float* bt = targ + (size_t)r0 * W + c;

        // ---- issue ALL tile loads up front: 12 float4 + 12 predicated
        //      halo scalars in flight before any consume ----
        float4 pv[NR], tv[NR];
        float  hp[NR], ht[NR];
        #pragma unroll
        for (int r = 0; r < NR; ++r) {
            int row = r0 - 1 + r;
            bool valid = (unsigned)row < (unsigned)H;
            const float* pp = bp + (ptrdiff_t)(r - 1) * W;
            const float* tt = bt + (ptrdiff_t)(r - 1) * W;
            pv[r] = valid ? *(const float4*)pp : make_float4(0.f, 0.f, 0.f, 0.f);
            tv[r] = valid ? *(const float4*)tt : make_float4(0.f, 0.f, 0.f, 0.f);
            float h1 = 0.f, h2 = 0.f;
            if (valid & haloCol) {
                const float* q1 = isL ? pp - 1 : pp + 4;
                const float* q2 = isL ? tt - 1 : tt + 4;
                h1 = *q1; h2 = *q2;
            }
            hp[r] = h1; ht[r] = h2;
        }

        // ---- compute with rolling 3-row Prep window ----
        Prep pA = fin(pv[0], hp[0], isL, isR);
        Prep tA = fin(tv[0], ht[0], isL, isR);
        Prep pB = fin(pv[1], hp[1], isL, isR);
        Prep tB = fin(tv[1], ht[1], isL, isR);

        float acc = 0.f;
        #pragma unroll
        for (int i = 0; i < TH; ++i) {
            Prep pC = fin(pv[i + 2], hp[i + 2], isL, isR);
            Prep tC = fin(tv[i + 2], ht[i + 2], isL, isR);

            float pe, te, d;
            pe = edge1(pA.dx0, pB.dx0, pC.dx0, pA.s0, pC.s0);
            te = edge1(tA.dx0, tB.dx0, tC.dx0, tA.s0, tC.s0);
            d = pe - te; acc = __fmaf_rn(d, d, acc);
            pe = edge1(pA.dx1, pB.dx1, pC.dx1, pA.s1, pC.s1);
            te = edge1(tA.dx1, tB.dx1, tC.dx1, tA.s1, tC.s1);
            d = pe - te; acc = __fmaf_rn(d, d, acc);
            pe = edge1(pA.dx2, pB.dx2, pC.dx2, pA.s2, pC.s2);
            te = edge1(tA.dx2, tB.dx2, tC.dx2, tA.s2, tC.s2);
            d = pe - te; acc = __fmaf_rn(d, d, acc);
            pe = edge1(pA.dx3, pB.dx3, pC.dx3, pA.s3, pC.s3);
            te = edge1(tA.dx3, tB.dx3, tC.dx3, tA.s3, tC.s3);
            d = pe - te; acc = __fmaf_rn(d, d, acc);

            pA = pB; pB = pC;
            tA = tB; tB = tC;
        }

        // wave reduce (width 64)
        #pragma unroll
        for (int m = 32; m; m >>= 1) acc += __shfl_xor(acc, m);

        __shared__ float wsum[BX / 64];
        if ((threadIdx.x & 63) == 0) wsum[threadIdx.x >> 6] = acc;
        __syncthreads();
        if (threadIdx.x == 0) {
            float s = 0.f;
            #pragma unroll
            for (int i = 0; i < BX / 64; ++i) s += wsum[i];
            ws[bid] = s;
        }
    } else {
        // ======================= keypoint block =======================
        int t = threadIdx.x;
        if (t >= 64) return;
        int k = (bid - NEDGE) * 64 + t;        // keypoint index 0..1023

        float gx = kp[2 * k];
        float gy = kp[2 * k + 1];
        float x = (gx + 1.f) * (W * 0.5f) - 0.5f;
        float y = (gy + 1.f) * (H * 0.5f) - 0.5f;
        float fx0 = floorf(x), fy0 = floorf(y);
        int x0 = (int)fx0, y0 = (int)fy0;
        int x1 = x0 + 1, y1 = y0 + 1;
        float wx1 = x - fx0, wx0 = 1.f - wx1;
        float wy1 = y - fy0, wy0 = 1.f - wy1;

        // 6x6 pred_seg patch around (y0, x0), zero-padded
        float sg[6][6];
        #pragma unroll
        for (int i = 0; i < 6; ++i) {
            int rr = y0 - 2 + i;
            #pragma unroll
            for (int j = 0; j < 6; ++j) {
                int cc = x0 - 2 + j;
                bool ok = (rr >= 0) & (rr < H) & (cc >= 0) & (cc < W);
                sg[i][j] = ok ? pred[(size_t)rr * W + cc] : 0.f;
            }
        }

        // 4x4 pred_edge for rows y0-1..y0+2, cols x0-1..x0+2 (0 when OOB)
        float e[4][4];
        #pragma unroll
        for (int i = 0; i < 4; ++i) {
            int rr = y0 - 1 + i;
            #pragma unroll
            for (int j = 0; j < 4; ++j) {
                int cc = x0 - 1 + j;
                if (rr < 0 || rr >= H || cc < 0 || cc >= W) { e[i][j] = 0.f; continue; }
                float ex = (sg[i][j + 2] - sg[i][j])
                         + 2.f * (sg[i + 1][j + 2] - sg[i + 1][j])
                         + (sg[i + 2][j + 2] - sg[i + 2][j]);
                float ey = (sg[i + 2][j] + 2.f * sg[i + 2][j + 1] + sg[i + 2][j + 2])
                         - (sg[i][j] + 2.f * sg[i][j + 1] + sg[i][j + 2]);
                e[i][j] = fast_sqrt(__fmaf_rn(ex, ex, ey * ey));
            }
        }

        // 2x2 distance-map values (3x3 box over pred_edge), zero-padded conv
        float dmap[2][2];
        #pragma unroll
        for (int a = 0; a < 2; ++a) {
            #pragma unroll
            for (int b = 0; b < 2; ++b) {
                float s = 0.f;
                #pragma unroll
                for (int i = 0; i < 3; ++i)
                    #pragma unroll
                    for (int j = 0; j < 3; ++j) s += e[a + i][b + j];
                dmap[a][b] = s;
            }
        }

        bool vx0 = (x0 >= 0) & (x0 < W), vx1 = (x1 >= 0) & (x1 < W);
        bool vy0 = (y0 >= 0) & (y0 < H), vy1 = (y1 >= 0) & (y1 < H);
        float v00 = (vx0 & vy0) ? dmap[0][0] : 0.f;
        float v01 = (vx1 & vy0) ? dmap[0][1] : 0.f;
        float v10 = (vx0 & vy1) ? dmap[1][0] : 0.f;
        float v11 = (vx1 & vy1) ? dmap[1][1] : 0.f;
        float kd = wx0 * wy0 * v00 + wx1 * wy0 * v01
                 + wx0 * wy1 * v10 + wx1 * wy1 * v11;

        // wave reduce 64 kd values
        #pragma unroll
        for (int m = 32; m; m >>= 1) kd += __shfl_xor(kd, m);
        if (t == 0) ws[NEDGE + (bid - NEDGE)] = kd;
    }
}

__global__ __launch_bounds__(256) void final_kernel(const float* __restrict__ ws,
                                                    float* __restrict__ out) {
    int t = threadIdx.x;
    float es = 0.f;
    #pragma unroll
    for (int i = 0; i < NEDGE / 256; ++i) es += ws[t + i * 256];
    float ks = (t < NKPB) ? ws[NEDGE + t] : 0.f;

    #pragma unroll
    for (int m = 32; m; m >>= 1) {
        es += __shfl_xor(es, m);
        ks += __shfl_xor(ks, m);
    }
    __shared__ float res[4], rks[4];
    int wid = t >> 6;
    if ((t & 63) == 0) { res[wid] = es; rks[wid] = ks; }
    __syncthreads();
    if (t == 0) {
        float e2 = res[0] + res[1] + res[2] + res[3];
        float k2 = rks[0] + rks[1] + rks[2] + rks[3];
        float edge_loss = e2 * (1.f / ((float)H * (float)W));
        float constraint_loss = k2 * (1.f / 1024.f);
        out[0] = MASK_W * edge_loss + KPT_W * constraint_loss;
    }
}

extern "C" void kernel_launch(void* const* d_in, const int* in_sizes, int n_in,
                              void* d_out, int out_size, void* d_ws, size_t ws_size,
                              hipStream_t stream) {
    const float* kp   = (const float*)d_in[0];
    const float* pred = (const float*)d_in[2];
    const float* targ = (const float*)d_in[3];
    float* out = (float*)d_out;
    float* ws  = (float*)d_ws;

    fused_kernel<<<NEDGE + NKPB, BX, 0, stream>>>(pred, targ, kp, ws);
    final_kernel<<<1, 256, 0, stream>>>(ws, out);
}